// Round 2
// baseline (177.717 us; speedup 1.0000x reference)
//
#include <hip/hip_runtime.h>

// grid [2,160,160,160,3] fp32; interior outputs (i,j,k) in 2..157 per axis.
//
// Structure: march in x with a per-thread register pipeline so each staged
// slice is read from LDS exactly ONCE (vs 5x for a 5-slice stencil ring):
//   - within-slice terms (hzz*, hyy*, hyz*) emitted at x = i
//   - hxy*/hxz* emitted at x = i+1 from dy/dz pipelined 2 steps (parity banks)
//   - hxx0 emitted at x = i+2 from v0 pipelined 4 steps
// LDS is SoA ([row][comp][z], padded strides) so each thread serves V=4
// consecutive z outputs from 18 ds_read_b128 + 8 ds_read_b64 per slice.
// Staging transposes AoS global -> SoA LDS via 3x float4 per 12 floats.
#define OY 480                    // 160*3
#define OX 76800                  // 160*480
#define SB 12288000               // 160*76800
#define JT 12                     // output rows (y) per block; 13 tiles
#define KQ 13                     // z-quads per row per block (KZ = 52); 3 tiles
#define IT 12                     // output slices (x) per block; 13 segs
#define NROW 16                   // JT + 4 halo rows
#define ZST 60                    // padded z stride (floats); 56 used
#define RST 180                   // row stride = 3*ZST
#define SLICE (NROW*RST)          // 2880 floats per slice buffer
#define CTHR (JT*KQ)              // 156 compute threads (V=4 pts each)
#define NGRP (NROW*14)            // 224 staging groups (12 floats each)
#define NBLK 1014                 // 2 * 13(jt) * 3(kt) * 13(is)
#define INV_SIZE (1.0f/22778496.0f)  // 2*156^3*3

__device__ __forceinline__ float4 ld4p(const float* p){ return *reinterpret_cast<const float4*>(p); }
__device__ __forceinline__ float2 ld2p(const float* p){ return *reinterpret_cast<const float2*>(p); }
__device__ __forceinline__ void st4p(float* p, float4 v){ *reinterpret_cast<float4*>(p) = v; }

// One x-step at compile-time buffer parity P. Reads slice x=i0-2+s from
// buf[P], prefetches slice x+1 into regs early, writes it to buf[P^1] late.
// V0a/V0b: v0 history (x-2 / x-4, same parity). DP[5][4]: dy0,dy1,dz0,dz1,dz2
// at x-2 (same parity bank => written 2 steps ago).
#define STEP(P, V0a, V0b, DP) { \
    const int s = 2*d + (P); \
    const bool doLoad = stg && (s <= 14); \
    float4 A4, B4, C4; \
    if (doLoad) { \
        const float* gp = G + (size_t)(i0 - 1 + s)*OX + gbase; \
        A4 = ld4p(gp); B4 = ld4p(gp+4); C4 = ld4p(gp+8); \
    } \
    if (act) { \
        const bool doWS = (s >= 2) && (s <= 13); \
        const bool doXY = (s >= 3) && (s <= 14); \
        const bool doXX = (s >= 4); \
        const float* L = lds + (P)*SLICE; \
        float v0c[4], dz0[4], dz1[4], dz2[4], dyc0[4], dyc1[4]; \
        { /* row j comp0 + rows j+-2 comp0 */ \
          float4 lo = ld4p(L+oj), hi = ld4p(L+oj+4); \
          float f[8] = {lo.x,lo.y,lo.z,lo.w,hi.x,hi.y,hi.z,hi.w}; \
          _Pragma("unroll") for (int v=0;v<4;++v){ v0c[v]=f[v+2]; dz0[v]=f[v+3]-f[v+1]; } \
          if (doWS) { \
            _Pragma("unroll") for (int v=0;v<4;++v){ float h=f[v+4]-2.f*f[v+2]+f[v]; cls2=fmaf(h,h,cls2); } \
            float2 pa=ld2p(L+oj+2*RST+2), pb=ld2p(L+oj+2*RST+4); \
            float2 ma=ld2p(L+oj-2*RST+2), mb=ld2p(L+oj-2*RST+4); \
            float hp[4]={pa.x,pa.y,pb.x,pb.y}, hm[4]={ma.x,ma.y,mb.x,mb.y}; \
            _Pragma("unroll") for (int v=0;v<4;++v){ float h=hp[v]-2.f*f[v+2]+hm[v]; cls2=fmaf(h,h,cls2); } \
          } \
        } \
        { /* row j comp1 + rows j+-2 comp1 */ \
          float4 lo = ld4p(L+oj+ZST), hi = ld4p(L+oj+ZST+4); \
          float f[8] = {lo.x,lo.y,lo.z,lo.w,hi.x,hi.y,hi.z,hi.w}; \
          _Pragma("unroll") for (int v=0;v<4;++v){ dz1[v]=f[v+3]-f[v+1]; } \
          if (doWS) { \
            _Pragma("unroll") for (int v=0;v<4;++v){ float h=f[v+4]-2.f*f[v+2]+f[v]; cls2=fmaf(h,h,cls2); } \
            float2 pa=ld2p(L+oj+2*RST+ZST+2), pb=ld2p(L+oj+2*RST+ZST+4); \
            float2 ma=ld2p(L+oj-2*RST+ZST+2), mb=ld2p(L+oj-2*RST+ZST+4); \
            float hp[4]={pa.x,pa.y,pb.x,pb.y}, hm[4]={ma.x,ma.y,mb.x,mb.y}; \
            _Pragma("unroll") for (int v=0;v<4;++v){ float h=hp[v]-2.f*f[v+2]+hm[v]; cls1=fmaf(h,h,cls1); } \
          } \
        } \
        { /* row j comp2 */ \
          float4 lo = ld4p(L+oj+2*ZST), hi = ld4p(L+oj+2*ZST+4); \
          float f[8] = {lo.x,lo.y,lo.z,lo.w,hi.x,hi.y,hi.z,hi.w}; \
          _Pragma("unroll") for (int v=0;v<4;++v){ dz2[v]=f[v+3]-f[v+1]; } \
          if (doWS) { \
            _Pragma("unroll") for (int v=0;v<4;++v){ float h=f[v+4]-2.f*f[v+2]+f[v]; cls1=fmaf(h,h,cls1); } \
          } \
        } \
        { /* rows j+-1 comp0: dy0 */ \
          float4 plo=ld4p(L+oj+RST), phi=ld4p(L+oj+RST+4); \
          float4 mlo=ld4p(L+oj-RST), mhi=ld4p(L+oj-RST+4); \
          float dyw[6]={plo.y-mlo.y, plo.z-mlo.z, plo.w-mlo.w, phi.x-mhi.x, phi.y-mhi.y, phi.z-mhi.z}; \
          _Pragma("unroll") for (int v=0;v<4;++v) dyc0[v]=dyw[v+1]; \
          if (doWS) { _Pragma("unroll") for (int v=0;v<4;++v){ float h=dyw[v+2]-dyw[v]; cls4=fmaf(h,h,cls4); } } \
        } \
        { /* rows j+-1 comp1: dy1 */ \
          float4 plo=ld4p(L+oj+RST+ZST), phi=ld4p(L+oj+RST+ZST+4); \
          float4 mlo=ld4p(L+oj-RST+ZST), mhi=ld4p(L+oj-RST+ZST+4); \
          float dyw[6]={plo.y-mlo.y, plo.z-mlo.z, plo.w-mlo.w, phi.x-mhi.x, phi.y-mhi.y, phi.z-mhi.z}; \
          _Pragma("unroll") for (int v=0;v<4;++v) dyc1[v]=dyw[v+1]; \
          if (doWS) { _Pragma("unroll") for (int v=0;v<4;++v){ float h=dyw[v+2]-dyw[v]; cls3=fmaf(h,h,cls3); } } \
        } \
        if (doWS) { /* rows j+-1 comp2: hyz2 only */ \
          float4 plo=ld4p(L+oj+RST+2*ZST), phi=ld4p(L+oj+RST+2*ZST+4); \
          float4 mlo=ld4p(L+oj-RST+2*ZST), mhi=ld4p(L+oj-RST+2*ZST+4); \
          float dyw[6]={plo.y-mlo.y, plo.z-mlo.z, plo.w-mlo.w, phi.x-mhi.x, phi.y-mhi.y, phi.z-mhi.z}; \
          _Pragma("unroll") for (int v=0;v<4;++v){ float h=dyw[v+2]-dyw[v]; cls1=fmaf(h,h,cls1); } \
        } \
        _Pragma("unroll") for (int v=0;v<4;++v) { \
          float o0=DP[0][v], o1=DP[1][v], o2=DP[2][v], o3=DP[3][v], o4=DP[4][v]; \
          if (doXY) { float h; \
            h=dyc0[v]-o0; cls3=fmaf(h,h,cls3); \
            h=dyc1[v]-o1; cls1=fmaf(h,h,cls1); \
            h=dz0[v]-o2;  cls3=fmaf(h,h,cls3); \
            h=dz1[v]-o3;  cls2=fmaf(h,h,cls2); \
            h=dz2[v]-o4;  cls1=fmaf(h,h,cls1); \
          } \
          DP[0][v]=dyc0[v]; DP[1][v]=dyc1[v]; DP[2][v]=dz0[v]; DP[3][v]=dz1[v]; DP[4][v]=dz2[v]; \
          float w2v=V0a[v], w4v=V0b[v]; \
          if (doXX) { float h=v0c[v]-2.f*w2v+w4v; cls1=fmaf(h,h,cls1); } \
          V0b[v]=w2v; V0a[v]=v0c[v]; \
        } \
    } \
    if (doLoad) { \
        float* Lw = lds + ((P)^1)*SLICE + lbase; \
        st4p(Lw,       make_float4(A4.x,A4.w,B4.z,C4.y)); \
        st4p(Lw+ZST,   make_float4(A4.y,B4.x,B4.w,C4.z)); \
        st4p(Lw+2*ZST, make_float4(A4.z,B4.y,C4.x,C4.w)); \
    } \
    __syncthreads(); \
}

__global__ __launch_bounds__(256)
void be_partials(const float* __restrict__ g, float* __restrict__ partial) {
    __shared__ float lds[2*SLICE];
    __shared__ float wsum[4];

    const int tid = threadIdx.x;
    const int bid = blockIdx.x;
    const int is = bid % 13;
    int r1 = bid / 13;
    const int kt = r1 % 3; r1 /= 3;
    const int jt = r1 % 13;
    const int bb = r1 / 13;

    const int j0  = 2 + jt*JT;     // first output y (rows j0-2 .. j0+13 staged)
    const int zlo = 52*kt;         // staged z range zlo .. zlo+55
    const int i0  = 2 + is*IT;     // first output x (slices i0-2 .. i0+13)
    const float* __restrict__ G = g + (size_t)bb*SB;

    // staging: 224 groups of 12 consecutive global floats (4 z x 3 comps)
    const bool stg = tid < NGRP;
    int gbase = 0, lbase = 0;
    if (stg) {
        int rr = tid/14, zq = tid - (tid/14)*14;
        gbase = (j0-2+rr)*OY + (zlo+4*zq)*3;
        lbase = rr*RST + 4*zq;
    }

    // compute mapping: thread -> (row cj, z-quad cq); 4 outputs k = zlo+2+4cq+v
    const bool act = tid < CTHR;
    int cj = tid/KQ, cq = tid - (tid/KQ)*KQ;
    if (!act) { cj = 0; cq = 0; }
    const int oj = (cj+2)*RST + 4*cq;   // row j, comp0 plane, window base

    // pipeline state (parity banks A=even step, B=odd step)
    float v0A0[4], v0A1[4], v0B0[4], v0B1[4];
    float dpA[5][4], dpB[5][4];
    #pragma unroll
    for (int v=0;v<4;++v){
        v0A0[v]=v0A1[v]=v0B0[v]=v0B1[v]=0.f;
        #pragma unroll
        for (int q=0;q<5;++q){ dpA[q][v]=0.f; dpB[q][v]=0.f; }
    }
    float cls1=0.f, cls2=0.f, cls3=0.f, cls4=0.f;

    // warmup: stage slice x = i0-2 into buf 0
    if (stg) {
        const float* gp = G + (size_t)(i0-2)*OX + gbase;
        float4 A4 = ld4p(gp), B4 = ld4p(gp+4), C4 = ld4p(gp+8);
        float* Lw = lds + lbase;
        st4p(Lw,       make_float4(A4.x,A4.w,B4.z,C4.y));
        st4p(Lw+ZST,   make_float4(A4.y,B4.x,B4.w,C4.z));
        st4p(Lw+2*ZST, make_float4(A4.z,B4.y,C4.x,C4.w));
    }
    __syncthreads();

    #pragma unroll 1
    for (int d = 0; d < 8; ++d) {
        STEP(0, v0A0, v0A1, dpA)
        STEP(1, v0B0, v0B1, dpB)
    }

    // fold weight classes (multiplicity 1,2,3,4; 0.0625 = (0.25)^2 per term)
    float sv = fmaf(2.f, cls2, cls1);
    sv = fmaf(3.f, cls3, sv);
    sv = fmaf(4.f, cls4, sv);
    sv *= 0.0625f;

    #pragma unroll
    for (int off = 32; off > 0; off >>= 1) sv += __shfl_down(sv, off, 64);
    if ((tid & 63) == 0) wsum[tid >> 6] = sv;
    __syncthreads();
    if (tid == 0)
        partial[bid] = (wsum[0] + wsum[1]) + (wsum[2] + wsum[3]);
}

__global__ __launch_bounds__(256)
void be_final(const float* __restrict__ partial, float* __restrict__ out) {
    float s = 0.0f;
    for (int i = threadIdx.x; i < NBLK; i += 256) s += partial[i];
    #pragma unroll
    for (int off = 32; off > 0; off >>= 1) s += __shfl_down(s, off, 64);
    __shared__ float ws[4];
    if ((threadIdx.x & 63) == 0) ws[threadIdx.x >> 6] = s;
    __syncthreads();
    if (threadIdx.x == 0)
        out[0] = ((ws[0] + ws[1]) + (ws[2] + ws[3])) * INV_SIZE;
}

extern "C" void kernel_launch(void* const* d_in, const int* in_sizes, int n_in,
                              void* d_out, int out_size, void* d_ws, size_t ws_size,
                              hipStream_t stream) {
    const float* grid = (const float*)d_in[0];
    float* out = (float*)d_out;
    float* partials = (float*)d_ws;    // 1014 floats

    be_partials<<<dim3(NBLK), dim3(256), 0, stream>>>(grid, partials);
    be_final<<<1, 256, 0, stream>>>(partials, out);
}

// Round 3
// 164.485 us; speedup vs baseline: 1.0804x; 1.0804x over previous
//
#include <hip/hip_runtime.h>

// grid [2,160,160,160,3] fp32; interior outputs (i,j,k) in 2..157 per axis.
//
// Register-pipelined x-march (each staged slice read from LDS exactly once):
//   - within-slice terms (hzz*, hyy*, hyz*) emitted at x = i      (s in [2,13])
//   - hxy*/hxz* at x = i+1 from dy/dz pipelined 2 steps (parity)  (s in [3,14])
//   - hxx0 at x = i+2 from v0 pipelined 4 steps                    (s >= 4)
// LDS slices are FULL-Z AoS rows (480 contiguous floats per y-row), so:
//   - staging: the slab per slice is ONE contiguous 4800-float global range
//     -> 5 coalesced float4 loads + 5 lane-linear ds_write_b128 (0 conflicts)
//   - compute: all ds_read_b128 are 16B-aligned (window start = 12*q floats);
//     row stride 480 == 0 mod 32 banks, quad stride 12 -> ~even bank groups
#define OY 480                    // floats per y-row (160 z * 3 comps)
#define OX 76800                  // floats per x-slice
#define SB 12288000               // floats per batch
#define JT 6                      // output rows (y) per block; 26 tiles
#define NROW 10                   // JT + 4 halo rows
#define IT 12                     // output slices (x) per block; 13 segs
#define NSEG 13
#define DATF4 1200                // real float4s per slice (10 rows * 120)
#define SLICEF 5120               // padded slice floats (1280 f4)
#define CTHR 234                  // 6 rows * 39 z-quads (V=4 outputs each)
#define NBLK 676                  // 2 * 26 * 13
#define INV_SIZE (1.0f/22778496.0f)  // 2*156^3*3

__device__ __forceinline__ float4 ld4p(const float* p){ return *reinterpret_cast<const float4*>(p); }
__device__ __forceinline__ void st4p(float* p, float4 v){ *reinterpret_cast<float4*>(p) = v; }

__device__ __forceinline__ void ld24(float* d, const float* p){
    float4 x0=ld4p(p), x1=ld4p(p+4), x2=ld4p(p+8), x3=ld4p(p+12), x4=ld4p(p+16), x5=ld4p(p+20);
    d[0]=x0.x; d[1]=x0.y; d[2]=x0.z; d[3]=x0.w;
    d[4]=x1.x; d[5]=x1.y; d[6]=x1.z; d[7]=x1.w;
    d[8]=x2.x; d[9]=x2.y; d[10]=x2.z; d[11]=x2.w;
    d[12]=x3.x; d[13]=x3.y; d[14]=x3.z; d[15]=x3.w;
    d[16]=x4.x; d[17]=x4.y; d[18]=x4.z; d[19]=x4.w;
    d[20]=x5.x; d[21]=x5.y; d[22]=x5.z; d[23]=x5.w;
}
__device__ __forceinline__ void ld16(float* d, const float* p){
    float4 x0=ld4p(p), x1=ld4p(p+4), x2=ld4p(p+8), x3=ld4p(p+12);
    d[0]=x0.x; d[1]=x0.y; d[2]=x0.z; d[3]=x0.w;
    d[4]=x1.x; d[5]=x1.y; d[6]=x1.z; d[7]=x1.w;
    d[8]=x2.x; d[9]=x2.y; d[10]=x2.z; d[11]=x2.w;
    d[12]=x3.x; d[13]=x3.y; d[14]=x3.z; d[15]=x3.w;
}

// One x-step at compile-time buffer parity P. Reads slice x=i0-2+s from
// buf[P]; prefetches slice x+1 into regs early; writes it to buf[P^1] late.
#define STEP(P, V0a, V0b, DP) { \
    const int s = 2*d + (P); \
    const bool doLoad = (s <= 14); \
    float4 a0, a1, a2, a3, a4; \
    if (doLoad) { \
        const float* bp = G + (size_t)(i0 - 1 + s) * OX; \
        a0 = ld4p(bp+gof0); a1 = ld4p(bp+gof1); a2 = ld4p(bp+gof2); \
        a3 = ld4p(bp+gof3); a4 = ld4p(bp+gof4); \
    } \
    if (act) { \
        const bool doWS = (s >= 2) && (s <= 13); \
        const bool doXY = (s >= 3) && (s <= 14); \
        const bool doXX = (s >= 4); \
        const float* Lr = lds + (P)*SLICEF + oj; \
        float fcn[24]; ld24(fcn, Lr); \
        float v0c[4], dzc0[4], dzc1[4], dzc2[4]; \
        _Pragma("unroll") for (int v=0; v<4; ++v) { \
            v0c[v]  = fcn[6+3*v]; \
            dzc0[v] = fcn[9+3*v]  - fcn[3+3*v]; \
            dzc1[v] = fcn[10+3*v] - fcn[4+3*v]; \
            dzc2[v] = fcn[11+3*v] - fcn[5+3*v]; \
        } \
        if (doWS) { \
            _Pragma("unroll") for (int v=0; v<4; ++v) { \
                float h0 = fcn[12+3*v] - 2.f*fcn[6+3*v] + fcn[3*v];   cls2 = fmaf(h0,h0,cls2); \
                float h1 = fcn[13+3*v] - 2.f*fcn[7+3*v] + fcn[1+3*v]; cls2 = fmaf(h1,h1,cls2); \
                float h2 = fcn[14+3*v] - 2.f*fcn[8+3*v] + fcn[2+3*v]; cls1 = fmaf(h2,h2,cls1); \
            } \
            float p2[16], m2[16]; \
            ld16(p2, Lr + 2*OY + 4); \
            ld16(m2, Lr - 2*OY + 4); \
            _Pragma("unroll") for (int v=0; v<4; ++v) { \
                float h0 = p2[2+3*v] - 2.f*fcn[6+3*v] + m2[2+3*v]; cls2 = fmaf(h0,h0,cls2); \
                float h1 = p2[3+3*v] - 2.f*fcn[7+3*v] + m2[3+3*v]; cls1 = fmaf(h1,h1,cls1); \
            } \
        } \
        float fp[24], fm[24]; \
        ld24(fp, Lr + OY); ld24(fm, Lr - OY); \
        float dyc0[4], dyc1[4]; \
        _Pragma("unroll") for (int v=0; v<4; ++v) { \
            dyc0[v] = fp[3*(v+2)]   - fm[3*(v+2)]; \
            dyc1[v] = fp[3*(v+2)+1] - fm[3*(v+2)+1]; \
        } \
        if (doWS) { \
            _Pragma("unroll") for (int v=0; v<4; ++v) { \
                float ha = (fp[3*(v+3)]   - fm[3*(v+3)])   - (fp[3*(v+1)]   - fm[3*(v+1)]);   cls4 = fmaf(ha,ha,cls4); \
                float hb = (fp[3*(v+3)+1] - fm[3*(v+3)+1]) - (fp[3*(v+1)+1] - fm[3*(v+1)+1]); cls3 = fmaf(hb,hb,cls3); \
                float hc = (fp[3*(v+3)+2] - fm[3*(v+3)+2]) - (fp[3*(v+1)+2] - fm[3*(v+1)+2]); cls1 = fmaf(hc,hc,cls1); \
            } \
        } \
        _Pragma("unroll") for (int v=0; v<4; ++v) { \
            if (doXY) { float h; \
                h = dyc0[v] - DP[0][v]; cls3 = fmaf(h,h,cls3); \
                h = dyc1[v] - DP[1][v]; cls1 = fmaf(h,h,cls1); \
                h = dzc0[v] - DP[2][v]; cls3 = fmaf(h,h,cls3); \
                h = dzc1[v] - DP[3][v]; cls2 = fmaf(h,h,cls2); \
                h = dzc2[v] - DP[4][v]; cls1 = fmaf(h,h,cls1); \
            } \
            DP[0][v] = dyc0[v]; DP[1][v] = dyc1[v]; \
            DP[2][v] = dzc0[v]; DP[3][v] = dzc1[v]; DP[4][v] = dzc2[v]; \
            float w2v = V0a[v], w4v = V0b[v]; \
            if (doXX) { float h = v0c[v] - 2.f*w2v + w4v; cls1 = fmaf(h,h,cls1); } \
            V0b[v] = w2v; V0a[v] = v0c[v]; \
        } \
    } \
    if (doLoad) { \
        float* Lw = lds + ((P)^1)*SLICEF; \
        st4p(Lw+lof0, a0); st4p(Lw+lof1, a1); st4p(Lw+lof2, a2); \
        st4p(Lw+lof3, a3); st4p(Lw+lof4, a4); \
    } \
    __syncthreads(); \
}

__global__ __launch_bounds__(256, 3)
void be_partials(const float* __restrict__ g, float* __restrict__ partial) {
    __shared__ float lds[2*SLICEF];
    __shared__ float wsum[4];

    const int tid = threadIdx.x;
    const int bid = blockIdx.x;
    const int is = bid % NSEG;
    int r1 = bid / NSEG;
    const int jt = r1 % 26;
    const int bb = r1 / 26;

    const int j0 = 2 + jt*JT;          // output rows j0..j0+5 (stage j0-2..j0+7)
    const int i0 = 2 + is*IT;          // output slices i0..i0+11
    // slab base: batch + first staged row; each slice's slab is 4800
    // contiguous floats at  + x*OX
    const float* __restrict__ G = g + (size_t)bb*SB + (size_t)(j0-2)*OY;

    // ---- staging offsets: 5 float4s per thread, lane-linear in LDS ----
    int gof0, gof1, gof2, gof3, gof4, lof0, lof1, lof2, lof3, lof4;
    {
        int f;
        f = tid;          gof0 = 4*(f < DATF4 ? f : DATF4-1); lof0 = 4*f;
        f = tid + 256;    gof1 = 4*(f < DATF4 ? f : DATF4-1); lof1 = 4*f;
        f = tid + 512;    gof2 = 4*(f < DATF4 ? f : DATF4-1); lof2 = 4*f;
        f = tid + 768;    gof3 = 4*(f < DATF4 ? f : DATF4-1); lof3 = 4*f;
        f = tid + 1024;   gof4 = 4*(f < DATF4 ? f : DATF4-1); lof4 = 4*f;
    }

    // ---- compute mapping: thread -> (row cj, z-quad cq); V=4 outputs ----
    const bool act = tid < CTHR;
    int cj = tid / 39, cq = tid - (tid/39)*39;
    if (!act) { cj = 0; cq = 0; }
    const int oj = (cj+2)*OY + 12*cq;   // center-row window base (float index)

    // pipeline state (parity banks: A = even step, B = odd step)
    float v0A0[4], v0A1[4], v0B0[4], v0B1[4];
    float dpA[5][4], dpB[5][4];
    #pragma unroll
    for (int v=0; v<4; ++v) {
        v0A0[v]=v0A1[v]=v0B0[v]=v0B1[v]=0.f;
        #pragma unroll
        for (int q=0; q<5; ++q) { dpA[q][v]=0.f; dpB[q][v]=0.f; }
    }
    float cls1=0.f, cls2=0.f, cls3=0.f, cls4=0.f;

    // warmup: stage slice x = i0-2 into buf 0
    {
        const float* bp = G + (size_t)(i0-2)*OX;
        float4 a0=ld4p(bp+gof0), a1=ld4p(bp+gof1), a2=ld4p(bp+gof2),
               a3=ld4p(bp+gof3), a4=ld4p(bp+gof4);
        st4p(lds+lof0, a0); st4p(lds+lof1, a1); st4p(lds+lof2, a2);
        st4p(lds+lof3, a3); st4p(lds+lof4, a4);
    }
    __syncthreads();

    #pragma unroll 1
    for (int d = 0; d < 8; ++d) {
        STEP(0, v0A0, v0A1, dpA)
        STEP(1, v0B0, v0B1, dpB)
    }

    // fold weight classes (term multiplicities 1,2,3,4; 0.0625 = (0.25)^2)
    float sv = fmaf(2.f, cls2, cls1);
    sv = fmaf(3.f, cls3, sv);
    sv = fmaf(4.f, cls4, sv);
    sv *= 0.0625f;

    #pragma unroll
    for (int off = 32; off > 0; off >>= 1) sv += __shfl_down(sv, off, 64);
    if ((tid & 63) == 0) wsum[tid >> 6] = sv;
    __syncthreads();
    if (tid == 0)
        partial[bid] = (wsum[0] + wsum[1]) + (wsum[2] + wsum[3]);
}

__global__ __launch_bounds__(256)
void be_final(const float* __restrict__ partial, float* __restrict__ out) {
    float s = 0.0f;
    for (int i = threadIdx.x; i < NBLK; i += 256) s += partial[i];
    #pragma unroll
    for (int off = 32; off > 0; off >>= 1) s += __shfl_down(s, off, 64);
    __shared__ float ws[4];
    if ((threadIdx.x & 63) == 0) ws[threadIdx.x >> 6] = s;
    __syncthreads();
    if (threadIdx.x == 0)
        out[0] = ((ws[0] + ws[1]) + (ws[2] + ws[3])) * INV_SIZE;
}

extern "C" void kernel_launch(void* const* d_in, const int* in_sizes, int n_in,
                              void* d_out, int out_size, void* d_ws, size_t ws_size,
                              hipStream_t stream) {
    const float* grid = (const float*)d_in[0];
    float* out = (float*)d_out;
    float* partials = (float*)d_ws;    // 676 floats

    be_partials<<<dim3(NBLK), dim3(256), 0, stream>>>(grid, partials);
    be_final<<<1, 256, 0, stream>>>(partials, out);
}